// Round 1
// baseline (228.799 us; speedup 1.0000x reference)
//
#include <hip/hip_runtime.h>

// Upsample2d (upfirdn2d, factor=2, down=1, k=[1,3,1] outer, gain*factor^2=4).
// The reference's reshapes reinterpret the contiguous (N,C,H,W) buffer, so the
// effective math (derived by index algebra on the reference chain):
//   out[n, c2, h2, w2] = sum_{u,v in 0..2} K[u][v] * T(a=h2+u-1, b=w2+v-1)
//   with ab=a-1, bb=b-1; T nonzero iff ab,bb in [0,510] and odd 128-block
//   ((ab>>7)&1 && (bb>>7)&1); then
//   T = x_n[(2*c2 + (ab>>8))*32768 + (ab&127)*256 + (bb>>8)*128 + (bb&127)]
// K = [[1,3,1],[3,9,3],[1,3,1]] * 4/25.
// Output (4,128,512,512) fp32; input per-n block 128*256*256 = 8388608 floats.

__global__ __launch_bounds__(256) void upfir2x_kernel(const float* __restrict__ x,
                                                      float* __restrict__ out) {
    const unsigned q = blockIdx.x * 256u + threadIdx.x;   // one float4 (4 outputs) per thread
    const unsigned n  = q >> 23;            // 2^23 quads per n  (33554432/4)
    const unsigned r  = q & 0x7FFFFFu;
    const unsigned c2 = r >> 16;            // 2^16 quads per channel-plane
    const unsigned r2 = r & 0xFFFFu;
    const unsigned h2 = r2 >> 7;            // 128 quads per row
    const unsigned w2 = (r2 & 127u) << 2;

    const float* __restrict__ xn = x + (size_t)n * 8388608u;

    float acc0 = 0.f, acc1 = 0.f, acc2 = 0.f, acc3 = 0.f;

    // column taps bb = w2-2 .. w2+3 (covers v=0..2 for the 4 outputs)
    const int bb0 = (int)w2 - 2;
    int  coff[6];
    bool cok[6];
#pragma unroll
    for (int k = 0; k < 6; ++k) {
        const int bb = bb0 + k;
        cok[k]  = ((unsigned)bb <= 510u) && (((bb >> 7) & 1) != 0);
        coff[k] = ((bb >> 8) << 7) + (bb & 127);   // (bb>>8)*128 + (bb&127)
    }

    const float KE = 4.f / 25.f;    // corner weight
    const float KM = 12.f / 25.f;   // edge weight
    const float KC = 36.f / 25.f;   // center weight

#pragma unroll
    for (int u = 0; u < 3; ++u) {
        const int ab = (int)h2 + u - 2;
        if ((unsigned)ab > 510u) continue;        // a outside [1,511] -> zero row
        if (((ab >> 7) & 1) == 0) continue;       // even 128-block -> zero-stuffed row
        const float* __restrict__ base =
            xn + (((size_t)(2u * c2 + (unsigned)(ab >> 8))) << 15)   // *32768
               + (size_t)((ab & 127) << 8);                          // *256
        float xv[6];
#pragma unroll
        for (int k = 0; k < 6; ++k) xv[k] = cok[k] ? base[coff[k]] : 0.f;
        const float w0 = (u == 1) ? KM : KE;   // K[u][0] == K[u][2]
        const float w1 = (u == 1) ? KC : KM;   // K[u][1]
        acc0 += w0 * xv[0] + w1 * xv[1] + w0 * xv[2];
        acc1 += w0 * xv[1] + w1 * xv[2] + w0 * xv[3];
        acc2 += w0 * xv[2] + w1 * xv[3] + w0 * xv[4];
        acc3 += w0 * xv[3] + w1 * xv[4] + w0 * xv[5];
    }

    float4 o = make_float4(acc0, acc1, acc2, acc3);
    *reinterpret_cast<float4*>(out + ((size_t)q << 2)) = o;
}

extern "C" void kernel_launch(void* const* d_in, const int* in_sizes, int n_in,
                              void* d_out, int out_size, void* d_ws, size_t ws_size,
                              hipStream_t stream) {
    const float* x   = (const float*)d_in[0];
    float*       out = (float*)d_out;
    // out_size = 4*128*512*512 = 134217728 elements; 4 per thread
    const unsigned nthreads = (unsigned)(out_size / 4);
    dim3 grid(nthreads / 256u), block(256u);
    hipLaunchKernelGGL(upfir2x_kernel, grid, block, 0, stream, x, out);
}

// Round 2
// 181.281 us; speedup vs baseline: 1.2621x; 1.2621x over previous
//
#include <hip/hip_runtime.h>

// Upsample2d (upfirdn2d, factor=2, down=1, k=[1,3,1] outer, gain*factor^2=4).
// Reference index algebra (validated in round 1, absmax 3.1e-2):
//   out[n, c2, h2, w2] = sum_{u,v in 0..2} K[u][v] * T(ab=h2+u-2, bb=w2+v-2)
//   T nonzero iff ab,bb in [0,510] AND in an odd 128-block ((x>>7)&1), then
//   T = x_n[(2*c2 + (ab>>8))*32768 + (ab&127)*256 + (bb>>8)*128 + (bb&127)]
//   K = [[1,3,1],[3,9,3],[1,3,1]] * 4/25.
//
// Round-2 change: the 18 lane-strided scalar loads (stride 16 B -> 4x TA
// address cycles each) are replaced by 2 coalesced float4 loads per row tap.
// Key fact: 128 | block period and quads are 4-aligned, so a 4-element tap
// quad never crosses a validity boundary -> per-quad uniform validity.
// Only exception: bb=511 (the last element of quad B=508) is out of range.

__global__ __launch_bounds__(256) void upfir2x_kernel(const float* __restrict__ x,
                                                      float* __restrict__ out) {
    const unsigned q = blockIdx.x * 256u + threadIdx.x;   // one float4 (4 outputs) per thread
    const unsigned n  = q >> 23;            // 2^23 quads per n
    const unsigned r  = q & 0x7FFFFFu;
    const unsigned c2 = r >> 16;            // 2^16 quads per channel-plane
    const unsigned r2 = r & 0xFFFFu;
    const unsigned h2 = r2 >> 7;            // 128 quads per output row (wave-uniform)
    const unsigned i  = r2 & 127u;          // quad index within row; w2 = 4*i

    const float* __restrict__ xn = x + (size_t)n * 8388608u;

    // Column tap quads: taps bb = 4i-2 .. 4i+3 live in quads BL=4i-4, BC=4i.
    const int BL = (int)(i << 2) - 4;
    const int BC = (int)(i << 2);
    const bool vL = (BL >= 0) && (((BL >> 7) & 1) != 0);
    const bool vC = (((BC >> 7) & 1) != 0);               // BC in [0,508] always
    const int offL = ((BL >> 8) << 7) + (BL & 127);       // (B>>8)*128 + (B&127)
    const int offC = ((BC >> 8) << 7) + (BC & 127);

    const float KE = 4.f / 25.f;    // corner
    const float KM = 12.f / 25.f;   // edge
    const float KC = 36.f / 25.f;   // center

    float acc0 = 0.f, acc1 = 0.f, acc2 = 0.f, acc3 = 0.f;

#pragma unroll
    for (int u = 0; u < 3; ++u) {
        const int ab = (int)h2 + u - 2;
        if ((unsigned)ab > 510u) continue;          // row out of range (wave-uniform)
        if (((ab >> 7) & 1) == 0) continue;         // even 128-block -> zero-stuffed
        const float* __restrict__ base =
            xn + (((size_t)(2u * c2 + (unsigned)(ab >> 8))) << 15)   // *32768
               + (size_t)((ab & 127) << 8);                          // *256

        float4 xl = vL ? *reinterpret_cast<const float4*>(base + offL)
                       : make_float4(0.f, 0.f, 0.f, 0.f);
        float4 xc = vC ? *reinterpret_cast<const float4*>(base + offC)
                       : make_float4(0.f, 0.f, 0.f, 0.f);
        if (i == 127u) xc.w = 0.f;                  // bb = 511 is out of range

        const float w0 = (u == 1) ? KM : KE;        // K[u][0] == K[u][2]
        const float w1 = (u == 1) ? KC : KM;        // K[u][1]
        // output w2+j uses taps bb = 4i-2+j, 4i-1+j, 4i+j
        acc0 += w0 * xl.z + w1 * xl.w + w0 * xc.x;
        acc1 += w0 * xl.w + w1 * xc.x + w0 * xc.y;
        acc2 += w0 * xc.x + w1 * xc.y + w0 * xc.z;
        acc3 += w0 * xc.y + w1 * xc.z + w0 * xc.w;
    }

    *reinterpret_cast<float4*>(out + ((size_t)q << 2)) =
        make_float4(acc0, acc1, acc2, acc3);
}

extern "C" void kernel_launch(void* const* d_in, const int* in_sizes, int n_in,
                              void* d_out, int out_size, void* d_ws, size_t ws_size,
                              hipStream_t stream) {
    const float* x   = (const float*)d_in[0];
    float*       out = (float*)d_out;
    const unsigned nthreads = (unsigned)(out_size / 4);   // 33554432
    dim3 grid(nthreads / 256u), block(256u);
    hipLaunchKernelGGL(upfir2x_kernel, grid, block, 0, stream, x, out);
}